// Round 15
// baseline (54.764 us; speedup 1.0000x reference)
//
#include <hip/hip_runtime.h>
#include <hip/hip_fp16.h>

#define HH 512
#define WW 512
#define NPIX (HH*WW)
#define NBANDS 32
#define BAND (HH/NBANDS)     // 16 output rows per wave (per chain)
#define NSTEP (BAND+10)      // 26 productive steps (last fin at s=25)
#define PINF2 0x7C007C00u    // packed f16 +inf
#define NINF2 0xFC00FC00u    // packed f16 -inf

// ---- packed f16 ops as VOP3P inline asm (proven rounds 8-14) ----
typedef unsigned uh2;
__device__ __forceinline__ uh2 pmin(uh2 a, uh2 b){ uh2 r; asm("v_pk_min_f16 %0, %1, %2" : "=v"(r) : "v"(a), "v"(b)); return r; }
__device__ __forceinline__ uh2 pmax(uh2 a, uh2 b){ uh2 r; asm("v_pk_max_f16 %0, %1, %2" : "=v"(r) : "v"(a), "v"(b)); return r; }
__device__ __forceinline__ uh2 padd(uh2 a, uh2 b){ uh2 r; asm("v_pk_add_f16 %0, %1, %2" : "=v"(r) : "v"(a), "v"(b)); return r; }
__device__ __forceinline__ uh2 psub(uh2 a, uh2 b){ uh2 r; asm("v_pk_add_f16 %0, %1, %2 neg_lo:[0,1] neg_hi:[0,1]" : "=v"(r) : "v"(a), "v"(b)); return r; }
__device__ __forceinline__ uh2 pnfma(uh2 s, uh2 d){ uh2 r; asm("v_pk_fma_f16 %0, %1, %2, %2 neg_lo:[1,0,0] neg_hi:[1,0,0]" : "=v"(r) : "v"(s), "v"(d)); return r; }
__device__ __forceinline__ uh2 pmin3(uh2 a, uh2 b, uh2 c){ return pmin(pmin(a,b),c); }
__device__ __forceinline__ uh2 pmax3(uh2 a, uh2 b, uh2 c){ return pmax(pmax(a,b),c); }
__device__ __forceinline__ uh2 alignh(uh2 lo, uh2 hi){ return (lo >> 16) | (hi << 16); }   // (lo.y, hi.x)
__device__ __forceinline__ uh2 pk2(float x, float y){
    __half2 h = __halves2half2(__float2half_rn(x), __float2half_rn(y));
    union { __half2 h; uh2 u; } c; c.h = h; return c.u;
}
__device__ __forceinline__ float lo_f(uh2 v){ union { uh2 u; __half2 h; } c; c.u = v; return __low2float(c.h); }
__device__ __forceinline__ float hi_f(uh2 v){ union { uh2 u; __half2 h; } c; c.u = v; return __high2float(c.h); }

// ---- DPP full-wave lane shifts (VALU, no DS pipe); invalid lane <- old ----
__device__ __forceinline__ uh2 dshr1(uh2 v, unsigned old){   // lane i <- lane i-1
    return (uh2)__builtin_amdgcn_update_dpp((int)old, (int)v, 0x138, 0xF, 0xF, false);
}
__device__ __forceinline__ uh2 dshl1(uh2 v, unsigned old){   // lane i <- lane i+1
    return (uh2)__builtin_amdgcn_update_dpp((int)old, (int)v, 0x130, 0xF, 0xF, false);
}

// one full 512-wide row: lane l holds halves [8l..8l+7] in 4 packed regs
struct R4 { uh2 a, b, c, d; };
__device__ __forceinline__ R4 r4splat(uh2 v){ R4 r; r.a=v; r.b=v; r.c=v; r.d=v; return r; }
__device__ __forceinline__ R4 ldrow(const float* p){
    float4 u = *(const float4*)p;
    float4 v = *(const float4*)(p + 4);
    R4 r; r.a = pk2(u.x,u.y); r.b = pk2(u.z,u.w); r.c = pk2(v.x,v.y); r.d = pk2(v.z,v.w);
    return r;
}
__device__ __forceinline__ R4 vmin3(const R4& x, const R4& y, const R4& z){
    R4 r; r.a=pmin3(x.a,y.a,z.a); r.b=pmin3(x.b,y.b,z.b); r.c=pmin3(x.c,y.c,z.c); r.d=pmin3(x.d,y.d,z.d); return r;
}
__device__ __forceinline__ R4 vmax3(const R4& x, const R4& y, const R4& z){
    R4 r; r.a=pmax3(x.a,y.a,z.a); r.b=pmax3(x.b,y.b,z.b); r.c=pmax3(x.c,y.c,z.c); r.d=pmax3(x.d,y.d,z.d); return r;
}
__device__ __forceinline__ R4 rmin(const R4& x, const R4& y){
    R4 r; r.a=pmin(x.a,y.a); r.b=pmin(x.b,y.b); r.c=pmin(x.c,y.c); r.d=pmin(x.d,y.d); return r;
}
__device__ __forceinline__ R4 relusub(const R4& p, const R4& d){
    R4 r; r.a=pmax(psub(p.a,d.a),0u); r.b=pmax(psub(p.b,d.b),0u);
          r.c=pmax(psub(p.c,d.c),0u); r.d=pmax(psub(p.d,d.d),0u); return r;
}
__device__ __forceinline__ void skupd2(R4& s, const R4& d){
    s.a = padd(s.a, pnfma(s.a,d.a));
    s.b = padd(s.b, pnfma(s.b,d.b));
    s.c = padd(s.c, pnfma(s.c,d.c));
    s.d = padd(s.d, pnfma(s.d,d.d));
}
__device__ __forceinline__ R4 hminLR(const R4& x){
    uh2 L  = dshr1(x.d, PINF2);
    uh2 Rv = dshl1(x.a, PINF2);
    uh2 s0=alignh(L,x.a), s1=alignh(x.a,x.b), s2=alignh(x.b,x.c), s3=alignh(x.c,x.d), s4=alignh(x.d,Rv);
    R4 m; m.a=pmin(s0,s1); m.b=pmin(s1,s2); m.c=pmin(s2,s3); m.d=pmin(s3,s4); return m;
}
__device__ __forceinline__ R4 hmax3w(const R4& x){
    uh2 L  = dshr1(x.d, NINF2);
    uh2 Rv = dshl1(x.a, NINF2);
    uh2 s0=alignh(L,x.a), s1=alignh(x.a,x.b), s2=alignh(x.b,x.c), s3=alignh(x.c,x.d), s4=alignh(x.d,Rv);
    R4 m; m.a=pmax3(s0,x.a,s1); m.b=pmax3(s1,x.b,s2); m.c=pmax3(s2,x.c,s3); m.d=pmax3(s3,x.d,s4); return m;
}
__device__ __forceinline__ void finred(const R4& skF, const float4& o1, const float4& o2,
                                       float& sa, float& sb){
    float c0=lo_f(skF.a), c1=hi_f(skF.a), c2=lo_f(skF.b), c3=hi_f(skF.b);
    float c4=lo_f(skF.c), c5=hi_f(skF.c), c6=lo_f(skF.d), c7=hi_f(skF.d);
    sa += ((c0+c1)+(c2+c3)) + ((c4+c5)+(c6+c7));
    sb += ((c0*o1.x + c1*o1.y) + (c2*o1.z + c3*o1.w))
        + ((c4*o2.x + c5*o2.y) + (c6*o2.z + c7*o2.w));
}

// ---------- FAST step, TWO chains fused (shared control flow -> wide blocks) ----------
__device__ __forceinline__ void step_fast2(
    int g, int s, int y0, int y1,
    const float* __restrict__ imgX, const float* __restrict__ othX,
    const float* __restrict__ imgY, const float* __restrict__ othY,
    R4& xi2, R4& xi1, R4& xf0,
    R4& xe1p, R4& xe1pp, R4& xe2p, R4& xe2pp, R4& xe3p, R4& xe3pp, R4& xe4p, R4& xe4pp,
    R4& xskB, R4& xskD1, R4& xskD2, R4& xskF,
    float4& xoc1, float4& xoc2, float4& xon1, float4& xon2,
    R4& yi2, R4& yi1, R4& yf0,
    R4& ye1p, R4& ye1pp, R4& ye2p, R4& ye2pp, R4& ye3p, R4& ye3pp, R4& ye4p, R4& ye4pp,
    R4& yskB, R4& yskD1, R4& yskD2, R4& yskF,
    float4& yoc1, float4& yoc2, float4& yon1, float4& yon2,
    float& saX, float& sbX, float& saY, float& sbY)
{
    R4 xi0 = xf0, yi0 = yf0;
    if (s + 2 < NSTEP) {
        xf0 = ldrow(imgX + (size_t)(g + 2) * WW);
        yf0 = ldrow(imgY + (size_t)(g + 2) * WW);
    }
    const int  yfr  = g - 5;
    const bool fin  = (yfr >= y0) && (yfr < y1);
    const bool finN = (yfr + 1 >= y0) && (yfr + 1 < y1);
    if (finN) {
        xon1 = *(const float4*)(othX + (size_t)(yfr + 1) * WW);
        xon2 = *(const float4*)(othX + (size_t)(yfr + 1) * WW + 4);
        yon1 = *(const float4*)(othY + (size_t)(yfr + 1) * WW);
        yon2 = *(const float4*)(othY + (size_t)(yfr + 1) * WW + 4);
    }

    R4 xe1n = rmin(vmin3(xi2, xi1, xi0), hminLR(xi1));
    R4 ye1n = rmin(vmin3(yi2, yi1, yi0), hminLR(yi1));
    R4 xd1  = hmax3w(vmax3(xe1pp, xe1p, xe1n));
    R4 yd1  = hmax3w(vmax3(ye1pp, ye1p, ye1n));
    xskB = relusub(xi2, xd1);
    yskB = relusub(yi2, yd1);

    R4 xe2n = rmin(vmin3(xe1pp, xe1p, xe1n), hminLR(xe1p));
    R4 ye2n = rmin(vmin3(ye1pp, ye1p, ye1n), hminLR(ye1p));
    R4 xd2  = hmax3w(vmax3(xe2pp, xe2p, xe2n));
    R4 yd2  = hmax3w(vmax3(ye2pp, ye2p, ye2n));
    skupd2(xskD1, relusub(xe1pp, xd2));
    skupd2(yskD1, relusub(ye1pp, yd2));

    R4 xe3n = rmin(vmin3(xe2pp, xe2p, xe2n), hminLR(xe2p));
    R4 ye3n = rmin(vmin3(ye2pp, ye2p, ye2n), hminLR(ye2p));
    R4 xd3  = hmax3w(vmax3(xe3pp, xe3p, xe3n));
    R4 yd3  = hmax3w(vmax3(ye3pp, ye3p, ye3n));
    skupd2(xskD2, relusub(xe2pp, xd3));
    skupd2(yskD2, relusub(ye2pp, yd3));

    R4 xe4n = rmin(vmin3(xe3pp, xe3p, xe3n), hminLR(xe3p));
    R4 ye4n = rmin(vmin3(ye3pp, ye3p, ye3n), hminLR(ye3p));
    R4 xd4  = hmax3w(vmax3(xe4pp, xe4p, xe4n));
    R4 yd4  = hmax3w(vmax3(ye4pp, ye4p, ye4n));
    skupd2(xskF, relusub(xe3pp, xd4));
    skupd2(yskF, relusub(ye3pp, yd4));

    if (fin) {
        finred(xskF, xoc1, xoc2, saX, sbX);
        finred(yskF, yoc1, yoc2, saY, sbY);
    }
    xi2 = xi1; xi1 = xi0;  yi2 = yi1; yi1 = yi0;
    xe1pp = xe1n; xe2pp = xe2n; xe3pp = xe3n; xe4pp = xe4n;
    ye1pp = ye1n; ye2pp = ye2n; ye3pp = ye3n; ye4pp = ye4n;
}

// ---------- GUARD step, TWO chains fused (bands 0 / NBANDS-1) ----------
__device__ __forceinline__ void step_guard2(
    int g, int s, int y0, int y1,
    const float* __restrict__ imgX, const float* __restrict__ othX,
    const float* __restrict__ imgY, const float* __restrict__ othY,
    R4& xi2, R4& xi1, R4& xf0,
    R4& xe1p, R4& xe1pp, R4& xe2p, R4& xe2pp, R4& xe3p, R4& xe3pp,
    R4& xh1p, R4& xh1pp, R4& xh2p, R4& xh2pp, R4& xh3p, R4& xh3pp, R4& xh4p, R4& xh4pp,
    R4& xskB, R4& xskD1, R4& xskD2, R4& xskF,
    float4& xoc1, float4& xoc2, float4& xon1, float4& xon2,
    R4& yi2, R4& yi1, R4& yf0,
    R4& ye1p, R4& ye1pp, R4& ye2p, R4& ye2pp, R4& ye3p, R4& ye3pp,
    R4& yh1p, R4& yh1pp, R4& yh2p, R4& yh2pp, R4& yh3p, R4& yh3pp, R4& yh4p, R4& yh4pp,
    R4& yskB, R4& yskD1, R4& yskD2, R4& yskF,
    float4& yoc1, float4& yoc2, float4& yon1, float4& yon2,
    float& saX, float& sbX, float& saY, float& sbY)
{
    R4 xi0 = xf0, yi0 = yf0;
    {
        const int gn = g + 2;
        const bool ld = (s + 2 < NSTEP) && (gn >= 0) && (gn < HH);
        if (ld) { xf0 = ldrow(imgX + (size_t)gn * WW); yf0 = ldrow(imgY + (size_t)gn * WW); }
        else    { xf0 = r4splat(PINF2); yf0 = r4splat(PINF2); }
    }
    const int  yfr  = g - 5;
    const bool fin  = (yfr >= y0) && (yfr < y1);
    const bool finN = (yfr + 1 >= y0) && (yfr + 1 < y1);
    if (finN) {
        xon1 = *(const float4*)(othX + (size_t)(yfr + 1) * WW);
        xon2 = *(const float4*)(othX + (size_t)(yfr + 1) * WW + 4);
        yon1 = *(const float4*)(othY + (size_t)(yfr + 1) * WW);
        yon2 = *(const float4*)(othY + (size_t)(yfr + 1) * WW + 4);
    }

    R4 xe1n = rmin(vmin3(xi2, xi1, xi0), hminLR(xi1));
    R4 ye1n = rmin(vmin3(yi2, yi1, yi0), hminLR(yi1));
    R4 xh1n = hmax3w(xe1n);
    R4 yh1n = hmax3w(ye1n);
    if ((unsigned)(g - 1) >= (unsigned)HH) {
        xe1n = r4splat(PINF2); xh1n = r4splat(NINF2);
        ye1n = r4splat(PINF2); yh1n = r4splat(NINF2);
    }
    R4 xd1 = vmax3(xh1pp, xh1p, xh1n);
    R4 yd1 = vmax3(yh1pp, yh1p, yh1n);
    xskB = relusub(xi2, xd1);
    yskB = relusub(yi2, yd1);

    R4 xe2n = rmin(vmin3(xe1pp, xe1p, xe1n), hminLR(xe1p));
    R4 ye2n = rmin(vmin3(ye1pp, ye1p, ye1n), hminLR(ye1p));
    R4 xh2n = hmax3w(xe2n);
    R4 yh2n = hmax3w(ye2n);
    if ((unsigned)(g - 2) >= (unsigned)HH) {
        xe2n = r4splat(PINF2); xh2n = r4splat(NINF2);
        ye2n = r4splat(PINF2); yh2n = r4splat(NINF2);
    }
    R4 xd2 = vmax3(xh2pp, xh2p, xh2n);
    R4 yd2 = vmax3(yh2pp, yh2p, yh2n);
    skupd2(xskD1, relusub(xe1pp, xd2));
    skupd2(yskD1, relusub(ye1pp, yd2));

    R4 xe3n = rmin(vmin3(xe2pp, xe2p, xe2n), hminLR(xe2p));
    R4 ye3n = rmin(vmin3(ye2pp, ye2p, ye2n), hminLR(ye2p));
    R4 xh3n = hmax3w(xe3n);
    R4 yh3n = hmax3w(ye3n);
    if ((unsigned)(g - 3) >= (unsigned)HH) {
        xe3n = r4splat(PINF2); xh3n = r4splat(NINF2);
        ye3n = r4splat(PINF2); yh3n = r4splat(NINF2);
    }
    R4 xd3 = vmax3(xh3pp, xh3p, xh3n);
    R4 yd3 = vmax3(yh3pp, yh3p, yh3n);
    skupd2(xskD2, relusub(xe2pp, xd3));
    skupd2(yskD2, relusub(ye2pp, yd3));

    R4 xe4n = rmin(vmin3(xe3pp, xe3p, xe3n), hminLR(xe3p));
    R4 ye4n = rmin(vmin3(ye3pp, ye3p, ye3n), hminLR(ye3p));
    R4 xh4n = hmax3w(xe4n);
    R4 yh4n = hmax3w(ye4n);
    if ((unsigned)(g - 4) >= (unsigned)HH) { xh4n = r4splat(NINF2); yh4n = r4splat(NINF2); }
    R4 xd4 = vmax3(xh4pp, xh4p, xh4n);
    R4 yd4 = vmax3(yh4pp, yh4p, yh4n);
    skupd2(xskF, relusub(xe3pp, xd4));
    skupd2(yskF, relusub(ye3pp, yd4));

    if (fin) {
        finred(xskF, xoc1, xoc2, saX, sbX);
        finred(yskF, yoc1, yoc2, saY, sbY);
    }
    xi2 = xi1; xi1 = xi0;  yi2 = yi1; yi1 = yi0;
    xe1pp = xe1n; xe2pp = xe2n; xe3pp = xe3n;
    xh1pp = xh1n; xh2pp = xh2n; xh3pp = xh3n; xh4pp = xh4n;
    ye1pp = ye1n; ye2pp = ye2n; ye3pp = ye3n;
    yh1pp = yh1n; yh2pp = yh2n; yh3pp = yh3n; yh4pp = yh4n;
}

// One wave = one (image, band) pair, BOTH chains (pred/true) interleaved for ILP.
// 1024 waves total; shared control flow; no LDS, no DS ops.
__global__ __launch_bounds__(256)
__attribute__((amdgpu_waves_per_eu(1, 2)))
void cldice_stream_k(const float* __restrict__ y_pred,
                     const float* __restrict__ y_true,
                     float2* __restrict__ partials, int B)
{
    const int lane = threadIdx.x & 63;
    const int wid  = threadIdx.x >> 6;
    const int wave = blockIdx.x * 4 + wid;
    const int nPer = B * NBANDS;
    if (wave >= nPer) return;
    const int band = wave / B;        // waves grouped by band -> uniform path per block
    const int im   = wave - band * B;
    const int y0 = band * BAND;
    const int y1 = y0 + BAND;

    const float* __restrict__ imgX = y_pred + (size_t)im * NPIX + lane * 8;  // chain 0
    const float* __restrict__ othX = y_true + (size_t)im * NPIX + lane * 8;
    const float* __restrict__ imgY = y_true + (size_t)im * NPIX + lane * 8;  // chain 1
    const float* __restrict__ othY = y_pred + (size_t)im * NPIX + lane * 8;

    R4 xsk0 = r4splat(0u), xsk1 = xsk0, xsk2 = xsk0, xsk3 = xsk0;
    R4 ysk0 = xsk0, ysk1 = xsk0, ysk2 = xsk0, ysk3 = xsk0;
    float saX = 0.f, sbX = 0.f, saY = 0.f, sbY = 0.f;
    const int g0 = y0 - 5;
    float4 z4 = make_float4(0,0,0,0);
    float4 xoA1 = z4, xoA2 = z4, xoB1 = z4, xoB2 = z4;
    float4 yoA1 = z4, yoA2 = z4, yoB1 = z4, yoB2 = z4;

    if (band == 0 || band == NBANDS - 1) {
        // -------- guarded path (image top/bottom) --------
        R4 xi2 = r4splat(PINF2), xi1 = xi2, yi2 = xi2, yi1 = xi2;
        R4 xe1A = xi2, xe1B = xi2, xe2A = xi2, xe2B = xi2, xe3A = xi2, xe3B = xi2;
        R4 ye1A = xi2, ye1B = xi2, ye2A = xi2, ye2B = xi2, ye3A = xi2, ye3B = xi2;
        R4 xh1A = r4splat(NINF2), xh1B = xh1A, xh2A = xh1A, xh2B = xh1A;
        R4 xh3A = xh1A, xh3B = xh1A, xh4A = xh1A, xh4B = xh1A;
        R4 yh1A = xh1A, yh1B = xh1A, yh2A = xh1A, yh2B = xh1A;
        R4 yh3A = xh1A, yh3B = xh1A, yh4A = xh1A, yh4B = xh1A;
        R4 xf0, xf1, yf0, yf1;
        if (g0 >= 0) { xf0 = ldrow(imgX + (size_t)g0 * WW); yf0 = ldrow(imgY + (size_t)g0 * WW); }
        else         { xf0 = r4splat(PINF2); yf0 = xf0; }
        if (g0 + 1 >= 0) { xf1 = ldrow(imgX + (size_t)(g0+1) * WW); yf1 = ldrow(imgY + (size_t)(g0+1) * WW); }
        else             { xf1 = r4splat(PINF2); yf1 = xf1; }

#define STG(U, XF, YF, XS0,XS1,XS2,XS3, YS0,YS1,YS2,YS3, XOC1,XOC2,XON1,XON2, YOC1,YOC2,YON1,YON2, XE1P,XE1PP,XE2P,XE2PP,XE3P,XE3PP, XH1P,XH1PP,XH2P,XH2PP,XH3P,XH3PP,XH4P,XH4PP, YE1P,YE1PP,YE2P,YE2PP,YE3P,YE3PP, YH1P,YH1PP,YH2P,YH2PP,YH3P,YH3PP,YH4P,YH4PP) \
        step_guard2(g0 + sbase + U, sbase + U, y0, y1, imgX, othX, imgY, othY, \
            xi2, xi1, XF, XE1P,XE1PP,XE2P,XE2PP,XE3P,XE3PP, XH1P,XH1PP,XH2P,XH2PP,XH3P,XH3PP,XH4P,XH4PP, \
            XS0,XS1,XS2,XS3, XOC1,XOC2,XON1,XON2, \
            yi2, yi1, YF, YE1P,YE1PP,YE2P,YE2PP,YE3P,YE3PP, YH1P,YH1PP,YH2P,YH2PP,YH3P,YH3PP,YH4P,YH4PP, \
            YS0,YS1,YS2,YS3, YOC1,YOC2,YON1,YON2, saX, sbX, saY, sbY)
#define STG_E(U, XS0,XS1,XS2,XS3, YS0,YS1,YS2,YS3) \
        STG(U, xf0, yf0, XS0,XS1,XS2,XS3, YS0,YS1,YS2,YS3, xoA1,xoA2,xoB1,xoB2, yoA1,yoA2,yoB1,yoB2, \
            xe1A,xe1B,xe2A,xe2B,xe3A,xe3B, xh1A,xh1B,xh2A,xh2B,xh3A,xh3B,xh4A,xh4B, \
            ye1A,ye1B,ye2A,ye2B,ye3A,ye3B, yh1A,yh1B,yh2A,yh2B,yh3A,yh3B,yh4A,yh4B)
#define STG_O(U, XS0,XS1,XS2,XS3, YS0,YS1,YS2,YS3) \
        STG(U, xf1, yf1, XS0,XS1,XS2,XS3, YS0,YS1,YS2,YS3, xoB1,xoB2,xoA1,xoA2, yoB1,yoB2,yoA1,yoA2, \
            xe1B,xe1A,xe2B,xe2A,xe3B,xe3A, xh1B,xh1A,xh2B,xh2A,xh3B,xh3A,xh4B,xh4A, \
            ye1B,ye1A,ye2B,ye2A,ye3B,ye3A, yh1B,yh1A,yh2B,yh2A,yh3B,yh3A,yh4B,yh4A)
        for (int sbase = 0; sbase < 24; sbase += 4) {
            STG_E(0, xsk1,xsk0,xsk3,xsk2, ysk1,ysk0,ysk3,ysk2);
            STG_O(1, xsk2,xsk1,xsk0,xsk3, ysk2,ysk1,ysk0,ysk3);
            STG_E(2, xsk3,xsk2,xsk1,xsk0, ysk3,ysk2,ysk1,ysk0);
            STG_O(3, xsk0,xsk3,xsk2,xsk1, ysk0,ysk3,ysk2,ysk1);
        }
        {   // tail: steps 24, 25
            const int sbase = 24;
            STG_E(0, xsk1,xsk0,xsk3,xsk2, ysk1,ysk0,ysk3,ysk2);
            STG_O(1, xsk2,xsk1,xsk0,xsk3, ysk2,ysk1,ysk0,ysk3);
        }
#undef STG_E
#undef STG_O
#undef STG
    } else {
        // -------- fast path (interior bands; all halo rows are real) --------
        R4 xi2 = ldrow(imgX + (size_t)g0 * WW), xi1 = xi2, xf0 = xi2;
        R4 yi2 = ldrow(imgY + (size_t)g0 * WW), yi1 = yi2, yf0 = yi2;
        R4 xf1 = ldrow(imgX + (size_t)(g0 + 1) * WW);
        R4 yf1 = ldrow(imgY + (size_t)(g0 + 1) * WW);
        R4 xe1A = r4splat(PINF2), xe1B = xe1A, xe2A = xe1A, xe2B = xe1A;
        R4 xe3A = xe1A, xe3B = xe1A, xe4A = xe1A, xe4B = xe1A;
        R4 ye1A = xe1A, ye1B = xe1A, ye2A = xe1A, ye2B = xe1A;
        R4 ye3A = xe1A, ye3B = xe1A, ye4A = xe1A, ye4B = xe1A;

#define STF(U, XF, YF, XS0,XS1,XS2,XS3, YS0,YS1,YS2,YS3, XOC1,XOC2,XON1,XON2, YOC1,YOC2,YON1,YON2, XE1P,XE1PP,XE2P,XE2PP,XE3P,XE3PP,XE4P,XE4PP, YE1P,YE1PP,YE2P,YE2PP,YE3P,YE3PP,YE4P,YE4PP) \
        step_fast2(g0 + sbase + U, sbase + U, y0, y1, imgX, othX, imgY, othY, \
            xi2, xi1, XF, XE1P,XE1PP,XE2P,XE2PP,XE3P,XE3PP,XE4P,XE4PP, \
            XS0,XS1,XS2,XS3, XOC1,XOC2,XON1,XON2, \
            yi2, yi1, YF, YE1P,YE1PP,YE2P,YE2PP,YE3P,YE3PP,YE4P,YE4PP, \
            YS0,YS1,YS2,YS3, YOC1,YOC2,YON1,YON2, saX, sbX, saY, sbY)
#define STF_E(U, XS0,XS1,XS2,XS3, YS0,YS1,YS2,YS3) \
        STF(U, xf0, yf0, XS0,XS1,XS2,XS3, YS0,YS1,YS2,YS3, xoA1,xoA2,xoB1,xoB2, yoA1,yoA2,yoB1,yoB2, \
            xe1A,xe1B,xe2A,xe2B,xe3A,xe3B,xe4A,xe4B, ye1A,ye1B,ye2A,ye2B,ye3A,ye3B,ye4A,ye4B)
#define STF_O(U, XS0,XS1,XS2,XS3, YS0,YS1,YS2,YS3) \
        STF(U, xf1, yf1, XS0,XS1,XS2,XS3, YS0,YS1,YS2,YS3, xoB1,xoB2,xoA1,xoA2, yoB1,yoB2,yoA1,yoA2, \
            xe1B,xe1A,xe2B,xe2A,xe3B,xe3A,xe4B,xe4A, ye1B,ye1A,ye2B,ye2A,ye3B,ye3A,ye4B,ye4A)
        for (int sbase = 0; sbase < 24; sbase += 4) {
            STF_E(0, xsk1,xsk0,xsk3,xsk2, ysk1,ysk0,ysk3,ysk2);
            STF_O(1, xsk2,xsk1,xsk0,xsk3, ysk2,ysk1,ysk0,ysk3);
            STF_E(2, xsk3,xsk2,xsk1,xsk0, ysk3,ysk2,ysk1,ysk0);
            STF_O(3, xsk0,xsk3,xsk2,xsk1, ysk0,ysk3,ysk2,ysk1);
        }
        {   // tail: steps 24, 25
            const int sbase = 24;
            STF_E(0, xsk1,xsk0,xsk3,xsk2, ysk1,ysk0,ysk3,ysk2);
            STF_O(1, xsk2,xsk1,xsk0,xsk3, ysk2,ysk1,ysk0,ysk3);
        }
#undef STF_E
#undef STF_O
#undef STF
    }

#pragma unroll
    for (int off = 32; off; off >>= 1) {
        saX += __shfl_down(saX, off);
        sbX += __shfl_down(sbX, off);
        saY += __shfl_down(saY, off);
        sbY += __shfl_down(sbY, off);
    }
    if (lane == 0) {
        partials[wave]        = make_float2(sbX, saX);   // chain 0 (skel_pred)
        partials[nPer + wave] = make_float2(sbY, saY);   // chain 1 (skel_true)
    }
}

__global__ void cldice_final_k(const float2* __restrict__ partials, int nW,
                               float* __restrict__ out)
{
    double s0 = 0, s1 = 0, s2 = 0, s3 = 0;
    for (int i = threadIdx.x; i < nW; i += 256) {
        float2 p = partials[i];        s0 += p.x; s1 += p.y;   // chain 0
        float2 q = partials[nW + i];   s2 += q.x; s3 += q.y;   // chain 1
    }
#pragma unroll
    for (int off = 32; off; off >>= 1) {
        s0 += __shfl_down(s0, off);
        s1 += __shfl_down(s1, off);
        s2 += __shfl_down(s2, off);
        s3 += __shfl_down(s3, off);
    }
    __shared__ double sm[4][4];
    int wid = threadIdx.x >> 6, lane = threadIdx.x & 63;
    if (lane == 0) { sm[0][wid] = s0; sm[1][wid] = s1; sm[2][wid] = s2; sm[3][wid] = s3; }
    __syncthreads();
    if (threadIdx.x == 0) {
        double S0 = sm[0][0] + sm[0][1] + sm[0][2] + sm[0][3];
        double S1 = sm[1][0] + sm[1][1] + sm[1][2] + sm[1][3];
        double S2 = sm[2][0] + sm[2][1] + sm[2][2] + sm[2][3];
        double S3 = sm[3][0] + sm[3][1] + sm[3][2] + sm[3][3];
        double tprec = (S0 + 1.0) / (S1 + 1.0);
        double tsens = (S2 + 1.0) / (S3 + 1.0);
        out[0] = (float)(1.0 - 2.0 * (tprec * tsens) / (tprec + tsens));
    }
}

extern "C" void kernel_launch(void* const* d_in, const int* in_sizes, int n_in,
                              void* d_out, int out_size, void* d_ws, size_t ws_size,
                              hipStream_t stream)
{
    const float* y_pred = (const float*)d_in[0];
    const float* y_true = (const float*)d_in[1];
    const int B = in_sizes[0] / NPIX;          // 32 images

    float2* partials = (float2*)d_ws;          // 2*B*NBANDS float2 = 16 KB
    const int nWaves = B * NBANDS;             // both chains per wave
    const int blocks = (nWaves + 3) / 4;       // 4 waves per 256-thread block
    cldice_stream_k<<<blocks, 256, 0, stream>>>(y_pred, y_true, partials, B);

    cldice_final_k<<<1, 256, 0, stream>>>(partials, B * NBANDS, (float*)d_out);
}

// Round 16
// 42.705 us; speedup vs baseline: 1.2824x; 1.2824x over previous
//
#include <hip/hip_runtime.h>
#include <hip/hip_fp16.h>

#define HH 512
#define WW 512
#define NPIX (HH*WW)
#define NBANDS 32
#define BAND (HH/NBANDS)     // 16 output rows per wave
#define NSTEP (BAND+10)      // 26 productive steps (last fin at s=25)
#define PINF2 0x7C007C00u    // packed f16 +inf
#define NINF2 0xFC00FC00u    // packed f16 -inf

// ---- packed f16 ops as VOP3P inline asm (proven rounds 8-15) ----
typedef unsigned uh2;
__device__ __forceinline__ uh2 pmin(uh2 a, uh2 b){ uh2 r; asm("v_pk_min_f16 %0, %1, %2" : "=v"(r) : "v"(a), "v"(b)); return r; }
__device__ __forceinline__ uh2 pmax(uh2 a, uh2 b){ uh2 r; asm("v_pk_max_f16 %0, %1, %2" : "=v"(r) : "v"(a), "v"(b)); return r; }
__device__ __forceinline__ uh2 padd(uh2 a, uh2 b){ uh2 r; asm("v_pk_add_f16 %0, %1, %2" : "=v"(r) : "v"(a), "v"(b)); return r; }
__device__ __forceinline__ uh2 psub(uh2 a, uh2 b){ uh2 r; asm("v_pk_add_f16 %0, %1, %2 neg_lo:[0,1] neg_hi:[0,1]" : "=v"(r) : "v"(a), "v"(b)); return r; }
__device__ __forceinline__ uh2 pnfma(uh2 s, uh2 d){ uh2 r; asm("v_pk_fma_f16 %0, %1, %2, %2 neg_lo:[1,0,0] neg_hi:[1,0,0]" : "=v"(r) : "v"(s), "v"(d)); return r; }
__device__ __forceinline__ uh2 pmin3(uh2 a, uh2 b, uh2 c){ return pmin(pmin(a,b),c); }
__device__ __forceinline__ uh2 pmax3(uh2 a, uh2 b, uh2 c){ return pmax(pmax(a,b),c); }
__device__ __forceinline__ uh2 alignh(uh2 lo, uh2 hi){ return (lo >> 16) | (hi << 16); }   // (lo.y, hi.x)
__device__ __forceinline__ uh2 pk2(float x, float y){
    __half2 h = __halves2half2(__float2half_rn(x), __float2half_rn(y));
    union { __half2 h; uh2 u; } c; c.h = h; return c.u;
}
__device__ __forceinline__ float lo_f(uh2 v){ union { uh2 u; __half2 h; } c; c.u = v; return __low2float(c.h); }
__device__ __forceinline__ float hi_f(uh2 v){ union { uh2 u; __half2 h; } c; c.u = v; return __high2float(c.h); }

// ---- DPP full-wave lane shifts (VALU, no DS pipe); invalid lane <- old ----
__device__ __forceinline__ uh2 dshr1(uh2 v, unsigned old){   // lane i <- lane i-1
    return (uh2)__builtin_amdgcn_update_dpp((int)old, (int)v, 0x138, 0xF, 0xF, false);
}
__device__ __forceinline__ uh2 dshl1(uh2 v, unsigned old){   // lane i <- lane i+1
    return (uh2)__builtin_amdgcn_update_dpp((int)old, (int)v, 0x130, 0xF, 0xF, false);
}

// one full 512-wide row: lane l holds halves [8l..8l+7] in 4 packed regs
struct R4 { uh2 a, b, c, d; };
__device__ __forceinline__ R4 r4splat(uh2 v){ R4 r; r.a=v; r.b=v; r.c=v; r.d=v; return r; }
// raw load (NO conversion -> no inline waitcnt; compiler sinks the wait to cvt)
__device__ __forceinline__ void ldraw(const float* p, float4& u, float4& v){
    u = *(const float4*)p; v = *(const float4*)(p + 4);
}
// convert at consume time (2 steps after the load was issued)
__device__ __forceinline__ R4 cvtrow(const float4& u, const float4& v){
    R4 r; r.a = pk2(u.x,u.y); r.b = pk2(u.z,u.w); r.c = pk2(v.x,v.y); r.d = pk2(v.z,v.w);
    return r;
}
__device__ __forceinline__ R4 vmin3(const R4& x, const R4& y, const R4& z){
    R4 r; r.a=pmin3(x.a,y.a,z.a); r.b=pmin3(x.b,y.b,z.b); r.c=pmin3(x.c,y.c,z.c); r.d=pmin3(x.d,y.d,z.d); return r;
}
__device__ __forceinline__ R4 vmax3(const R4& x, const R4& y, const R4& z){
    R4 r; r.a=pmax3(x.a,y.a,z.a); r.b=pmax3(x.b,y.b,z.b); r.c=pmax3(x.c,y.c,z.c); r.d=pmax3(x.d,y.d,z.d); return r;
}
__device__ __forceinline__ R4 rmin(const R4& x, const R4& y){
    R4 r; r.a=pmin(x.a,y.a); r.b=pmin(x.b,y.b); r.c=pmin(x.c,y.c); r.d=pmin(x.d,y.d); return r;
}
__device__ __forceinline__ R4 relusub(const R4& p, const R4& d){
    R4 r; r.a=pmax(psub(p.a,d.a),0u); r.b=pmax(psub(p.b,d.b),0u);
          r.c=pmax(psub(p.c,d.c),0u); r.d=pmax(psub(p.d,d.d),0u); return r;
}
// s += d*(1-s)  (relu provably redundant for s,d in [0,1])
__device__ __forceinline__ void skupd2(R4& s, const R4& d){
    s.a = padd(s.a, pnfma(s.a,d.a));
    s.b = padd(s.b, pnfma(s.b,d.b));
    s.c = padd(s.c, pnfma(s.c,d.c));
    s.d = padd(s.d, pnfma(s.d,d.d));
}
__device__ __forceinline__ R4 hminLR(const R4& x){
    uh2 L  = dshr1(x.d, PINF2);
    uh2 Rv = dshl1(x.a, PINF2);
    uh2 s0=alignh(L,x.a), s1=alignh(x.a,x.b), s2=alignh(x.b,x.c), s3=alignh(x.c,x.d), s4=alignh(x.d,Rv);
    R4 m; m.a=pmin(s0,s1); m.b=pmin(s1,s2); m.c=pmin(s2,s3); m.d=pmin(s3,s4); return m;
}
__device__ __forceinline__ R4 hmax3w(const R4& x){
    uh2 L  = dshr1(x.d, NINF2);
    uh2 Rv = dshl1(x.a, NINF2);
    uh2 s0=alignh(L,x.a), s1=alignh(x.a,x.b), s2=alignh(x.b,x.c), s3=alignh(x.c,x.d), s4=alignh(x.d,Rv);
    R4 m; m.a=pmax3(s0,x.a,s1); m.b=pmax3(s1,x.b,s2); m.c=pmax3(s2,x.c,s3); m.d=pmax3(s3,x.d,s4); return m;
}
__device__ __forceinline__ void finred(const R4& skF, const float4& o1, const float4& o2,
                                       float& sa, float& sb){
    float c0=lo_f(skF.a), c1=hi_f(skF.a), c2=lo_f(skF.b), c3=hi_f(skF.b);
    float c4=lo_f(skF.c), c5=hi_f(skF.c), c6=lo_f(skF.d), c7=hi_f(skF.d);
    sa += ((c0+c1)+(c2+c3)) + ((c4+c5)+(c6+c7));
    sb += ((c0*o1.x + c1*o1.y) + (c2*o1.z + c3*o1.w))
        + ((c4*o2.x + c5*o2.y) + (c6*o2.z + c7*o2.w));
}

// ---------- FAST step: interior bands, no row guards ----------
// pr1/pr2 = raw float4s of row g (loaded 2 steps ago); converted HERE, then
// reused as the staging buffer for row g+2 (caller alternates pA/pB pairs).
__device__ __forceinline__ void step_fast(
    int g, int y0, int y1,
    const float* __restrict__ img, const float* __restrict__ oth,
    R4& i2, R4& i1, float4& pr1, float4& pr2,
    R4& e1p, R4& e1pp, R4& e2p, R4& e2pp, R4& e3p, R4& e3pp, R4& e4p, R4& e4pp,
    R4& skB, R4& skD1, R4& skD2, R4& skF,
    float4& oc1, float4& oc2, float4& on1, float4& on2,
    float& sa, float& sb)
{
    R4 i0 = cvtrow(pr1, pr2);                          // wait lands here (2-step-old load)
    {   // issue load of row g+2 into the freed staging pair (clamped; value
        // unused when beyond NSTEP — rows stay inside the image for interior bands)
        int gn = (g + 2 < HH) ? (g + 2) : (HH - 1);
        ldraw(img + (size_t)gn * WW, pr1, pr2);
    }
    const int  yf   = g - 5;
    const bool fin  = (yf >= y0) && (yf < y1);
    const bool finN = (yf + 1 >= y0) && (yf + 1 < y1);
    if (finN) {                                        // other-row 1 step early (raw)
        on1 = *(const float4*)(oth + (size_t)(yf + 1) * WW);
        on2 = *(const float4*)(oth + (size_t)(yf + 1) * WW + 4);
    }

    R4 e1n = rmin(vmin3(i2, i1, i0), hminLR(i1));
    R4 d1  = hmax3w(vmax3(e1pp, e1p, e1n));            // dilate(e1) @ g-2
    skB = relusub(i2, d1);

    R4 e2n = rmin(vmin3(e1pp, e1p, e1n), hminLR(e1p));
    R4 d2  = hmax3w(vmax3(e2pp, e2p, e2n));            // @ g-3
    skupd2(skD1, relusub(e1pp, d2));

    R4 e3n = rmin(vmin3(e2pp, e2p, e2n), hminLR(e2p));
    R4 d3  = hmax3w(vmax3(e3pp, e3p, e3n));            // @ g-4
    skupd2(skD2, relusub(e2pp, d3));

    R4 e4n = rmin(vmin3(e3pp, e3p, e3n), hminLR(e3p));
    R4 d4  = hmax3w(vmax3(e4pp, e4p, e4n));            // @ g-5
    skupd2(skF, relusub(e3pp, d4));

    if (fin) finred(skF, oc1, oc2, sa, sb);

    i2 = i1; i1 = i0;
    e1pp = e1n; e2pp = e2n; e3pp = e3n; e4pp = e4n;    // caller swaps (p,pp)
}

// ---------- GUARD step: bands 0 / NBANDS-1 ----------
__device__ __forceinline__ void step_guard(
    int g, int y0, int y1,
    const float* __restrict__ img, const float* __restrict__ oth,
    R4& i2, R4& i1, float4& pr1, float4& pr2,
    R4& e1p, R4& e1pp, R4& e2p, R4& e2pp, R4& e3p, R4& e3pp,
    R4& h1p, R4& h1pp, R4& h2p, R4& h2pp, R4& h3p, R4& h3pp,
    R4& h4p, R4& h4pp,
    R4& skB, R4& skD1, R4& skD2, R4& skF,
    float4& oc1, float4& oc2, float4& on1, float4& on2,
    float& sa, float& sb)
{
    // consume-time select reproduces the old load-time +inf splat exactly
    R4 i0 = ((unsigned)g < (unsigned)HH) ? cvtrow(pr1, pr2) : r4splat(PINF2);
    {   // clamped-address load (value discarded at consume when OOB)
        int gn = g + 2;
        gn = gn < 0 ? 0 : (gn >= HH ? HH - 1 : gn);
        ldraw(img + (size_t)gn * WW, pr1, pr2);
    }
    const int  yf   = g - 5;
    const bool fin  = (yf >= y0) && (yf < y1);
    const bool finN = (yf + 1 >= y0) && (yf + 1 < y1);
    if (finN) {
        on1 = *(const float4*)(oth + (size_t)(yf + 1) * WW);
        on2 = *(const float4*)(oth + (size_t)(yf + 1) * WW + 4);
    }

    R4 e1n = rmin(vmin3(i2, i1, i0), hminLR(i1));
    R4 h1n = hmax3w(e1n);
    if ((unsigned)(g - 1) >= (unsigned)HH) { e1n = r4splat(PINF2); h1n = r4splat(NINF2); }
    R4 d1 = vmax3(h1pp, h1p, h1n);
    skB = relusub(i2, d1);

    R4 e2n = rmin(vmin3(e1pp, e1p, e1n), hminLR(e1p));
    R4 h2n = hmax3w(e2n);
    if ((unsigned)(g - 2) >= (unsigned)HH) { e2n = r4splat(PINF2); h2n = r4splat(NINF2); }
    R4 d2 = vmax3(h2pp, h2p, h2n);
    skupd2(skD1, relusub(e1pp, d2));

    R4 e3n = rmin(vmin3(e2pp, e2p, e2n), hminLR(e2p));
    R4 h3n = hmax3w(e3n);
    if ((unsigned)(g - 3) >= (unsigned)HH) { e3n = r4splat(PINF2); h3n = r4splat(NINF2); }
    R4 d3 = vmax3(h3pp, h3p, h3n);
    skupd2(skD2, relusub(e2pp, d3));

    R4 e4n = rmin(vmin3(e3pp, e3p, e3n), hminLR(e3p));
    R4 h4n = hmax3w(e4n);
    if ((unsigned)(g - 4) >= (unsigned)HH) { h4n = r4splat(NINF2); }
    R4 d4 = vmax3(h4pp, h4p, h4n);
    skupd2(skF, relusub(e3pp, d4));

    if (fin) finred(skF, oc1, oc2, sa, sb);

    i2 = i1; i1 = i0;
    e1pp = e1n; e2pp = e2n; e3pp = e3n;
    h1pp = h1n; h2pp = h2n; h3pp = h3n; h4pp = h4n;
}

__global__ __launch_bounds__(256, 2)
void cldice_stream_k(const float* __restrict__ y_pred,
                     const float* __restrict__ y_true,
                     float2* __restrict__ partials, int B)
{
    const int lane = threadIdx.x & 63;
    const int wid  = threadIdx.x >> 6;
    const int wave = blockIdx.x * 4 + wid;
    const int nPerChain = B * NBANDS;
    if (wave >= 2 * nPerChain) return;
    const int chain = wave / nPerChain;
    const int rem   = wave - chain * nPerChain;
    const int im    = rem >> 5;                 // NBANDS == 32
    const int band  = rem & (NBANDS - 1);
    const int y0 = band * BAND;
    const int y1 = y0 + BAND;

    const float* __restrict__ img = (chain ? y_true : y_pred) + (size_t)im * NPIX + lane * 8;
    const float* __restrict__ oth = (chain ? y_pred : y_true) + (size_t)im * NPIX + lane * 8;

    R4 sk0 = r4splat(0u), sk1 = sk0, sk2 = sk0, sk3 = sk0;
    float sa = 0.f, sb = 0.f;
    const int g0 = y0 - 5;
    float4 oA1 = make_float4(0,0,0,0), oA2 = oA1, oB1 = oA1, oB2 = oA1;

    // raw staging pairs: pA = row consumed at even steps, pB = odd steps
    float4 pA1, pA2, pB1, pB2;
    {
        int r0 = g0 < 0 ? 0 : g0;
        int r1 = g0 + 1 < 0 ? 0 : g0 + 1;
        ldraw(img + (size_t)r0 * WW, pA1, pA2);
        ldraw(img + (size_t)r1 * WW, pB1, pB2);
    }

    if (band == 0 || band == NBANDS - 1) {
        // -------- guarded path (image top/bottom) --------
        R4 i2 = r4splat(PINF2), i1 = i2;
        R4 e1A = i2, e1B = i2, e2A = i2, e2B = i2, e3A = i2, e3B = i2;
        R4 h1A = r4splat(NINF2), h1B = h1A, h2A = h1A, h2B = h1A;
        R4 h3A = h1A, h3B = h1A, h4A = h1A, h4B = h1A;

#define STEPG(U, E1P,E1PP, E2P,E2PP, E3P,E3PP, H1P,H1PP, H2P,H2PP, H3P,H3PP, H4P,H4PP, SKB,SKD1,SKD2,SKF, PR1,PR2, OC1,OC2,ON1,ON2) \
        step_guard(g0 + sbase + U, y0, y1, img, oth, i2, i1, PR1, PR2, \
                   E1P,E1PP, E2P,E2PP, E3P,E3PP, H1P,H1PP, H2P,H2PP, H3P,H3PP, H4P,H4PP, \
                   SKB,SKD1,SKD2,SKF, OC1,OC2,ON1,ON2, sa, sb)
        for (int sbase = 0; sbase < 24; sbase += 4) {
            STEPG(0, e1A,e1B, e2A,e2B, e3A,e3B, h1A,h1B, h2A,h2B, h3A,h3B, h4A,h4B, sk1,sk0,sk3,sk2, pA1,pA2, oA1,oA2,oB1,oB2);
            STEPG(1, e1B,e1A, e2B,e2A, e3B,e3A, h1B,h1A, h2B,h2A, h3B,h3A, h4B,h4A, sk2,sk1,sk0,sk3, pB1,pB2, oB1,oB2,oA1,oA2);
            STEPG(2, e1A,e1B, e2A,e2B, e3A,e3B, h1A,h1B, h2A,h2B, h3A,h3B, h4A,h4B, sk3,sk2,sk1,sk0, pA1,pA2, oA1,oA2,oB1,oB2);
            STEPG(3, e1B,e1A, e2B,e2A, e3B,e3A, h1B,h1A, h2B,h2A, h3B,h3A, h4B,h4A, sk0,sk3,sk2,sk1, pB1,pB2, oB1,oB2,oA1,oA2);
        }
        {   // tail: steps 24, 25 (last fin at 25)
            const int sbase = 24;
            STEPG(0, e1A,e1B, e2A,e2B, e3A,e3B, h1A,h1B, h2A,h2B, h3A,h3B, h4A,h4B, sk1,sk0,sk3,sk2, pA1,pA2, oA1,oA2,oB1,oB2);
            STEPG(1, e1B,e1A, e2B,e2A, e3B,e3A, h1B,h1A, h2B,h2A, h3B,h3A, h4B,h4A, sk2,sk1,sk0,sk3, pB1,pB2, oB1,oB2,oA1,oA2);
        }
#undef STEPG
    } else {
        // -------- fast path (interior bands; all rows real; init outside frontier) --------
        R4 i2 = r4splat(PINF2), i1 = i2;
        R4 e1A = i2, e1B = i2, e2A = i2, e2B = i2;
        R4 e3A = i2, e3B = i2, e4A = i2, e4B = i2;

#define STEPF(U, E1P,E1PP, E2P,E2PP, E3P,E3PP, E4P,E4PP, SKB,SKD1,SKD2,SKF, PR1,PR2, OC1,OC2,ON1,ON2) \
        step_fast(g0 + sbase + U, y0, y1, img, oth, i2, i1, PR1, PR2, \
                  E1P,E1PP, E2P,E2PP, E3P,E3PP, E4P,E4PP, SKB,SKD1,SKD2,SKF, \
                  OC1,OC2,ON1,ON2, sa, sb)
        for (int sbase = 0; sbase < 24; sbase += 4) {
            STEPF(0, e1A,e1B, e2A,e2B, e3A,e3B, e4A,e4B, sk1,sk0,sk3,sk2, pA1,pA2, oA1,oA2,oB1,oB2);
            STEPF(1, e1B,e1A, e2B,e2A, e3B,e3A, e4B,e4A, sk2,sk1,sk0,sk3, pB1,pB2, oB1,oB2,oA1,oA2);
            STEPF(2, e1A,e1B, e2A,e2B, e3A,e3B, e4A,e4B, sk3,sk2,sk1,sk0, pA1,pA2, oA1,oA2,oB1,oB2);
            STEPF(3, e1B,e1A, e2B,e2A, e3B,e3A, e4B,e4A, sk0,sk3,sk2,sk1, pB1,pB2, oB1,oB2,oA1,oA2);
        }
        {   // tail: steps 24, 25
            const int sbase = 24;
            STEPF(0, e1A,e1B, e2A,e2B, e3A,e3B, e4A,e4B, sk1,sk0,sk3,sk2, pA1,pA2, oA1,oA2,oB1,oB2);
            STEPF(1, e1B,e1A, e2B,e2A, e3B,e3A, e4B,e4A, sk2,sk1,sk0,sk3, pB1,pB2, oB1,oB2,oA1,oA2);
        }
#undef STEPF
    }

#pragma unroll
    for (int off = 32; off; off >>= 1) {
        sa += __shfl_down(sa, off);
        sb += __shfl_down(sb, off);
    }
    if (lane == 0) partials[wave] = make_float2(sb, sa);   // (.x = sum skel*other, .y = sum skel)
}

__global__ void cldice_final_k(const float2* __restrict__ partials, int nW,
                               float* __restrict__ out)
{
    double s0 = 0, s1 = 0, s2 = 0, s3 = 0;
    for (int i = threadIdx.x; i < nW; i += 256) {
        float2 p = partials[i];        s0 += p.x; s1 += p.y;   // chain 0: skel_pred
        float2 q = partials[nW + i];   s2 += q.x; s3 += q.y;   // chain 1: skel_true
    }
#pragma unroll
    for (int off = 32; off; off >>= 1) {
        s0 += __shfl_down(s0, off);
        s1 += __shfl_down(s1, off);
        s2 += __shfl_down(s2, off);
        s3 += __shfl_down(s3, off);
    }
    __shared__ double sm[4][4];
    int wid = threadIdx.x >> 6, lane = threadIdx.x & 63;
    if (lane == 0) { sm[0][wid] = s0; sm[1][wid] = s1; sm[2][wid] = s2; sm[3][wid] = s3; }
    __syncthreads();
    if (threadIdx.x == 0) {
        double S0 = sm[0][0] + sm[0][1] + sm[0][2] + sm[0][3];
        double S1 = sm[1][0] + sm[1][1] + sm[1][2] + sm[1][3];
        double S2 = sm[2][0] + sm[2][1] + sm[2][2] + sm[2][3];
        double S3 = sm[3][0] + sm[3][1] + sm[3][2] + sm[3][3];
        double tprec = (S0 + 1.0) / (S1 + 1.0);
        double tsens = (S2 + 1.0) / (S3 + 1.0);
        out[0] = (float)(1.0 - 2.0 * (tprec * tsens) / (tprec + tsens));
    }
}

extern "C" void kernel_launch(void* const* d_in, const int* in_sizes, int n_in,
                              void* d_out, int out_size, void* d_ws, size_t ws_size,
                              hipStream_t stream)
{
    const float* y_pred = (const float*)d_in[0];
    const float* y_true = (const float*)d_in[1];
    const int B = in_sizes[0] / NPIX;          // 32 images

    float2* partials = (float2*)d_ws;          // 2*B*NBANDS float2 = 16 KB
    const int nWaves = 2 * B * NBANDS;
    const int blocks = (nWaves + 3) / 4;       // 4 waves per 256-thread block
    cldice_stream_k<<<blocks, 256, 0, stream>>>(y_pred, y_true, partials, B);

    cldice_final_k<<<1, 256, 0, stream>>>(partials, B * NBANDS, (float*)d_out);
}

// Round 17
// 39.949 us; speedup vs baseline: 1.3708x; 1.0690x over previous
//
#include <hip/hip_runtime.h>
#include <hip/hip_fp16.h>

#define HH 512
#define WW 512
#define NPIX (HH*WW)
#define NBANDS 32
#define BAND (HH/NBANDS)     // 16 output rows per wave
#define NSTEP (BAND+10)      // 26 productive steps (last fin at s=25)
#define PINF2 0x7C007C00u    // packed f16 +inf
#define NINF2 0xFC00FC00u    // packed f16 -inf

// ---- packed f16 ops as VOP3P inline asm (proven rounds 8-16) ----
typedef unsigned uh2;
__device__ __forceinline__ uh2 pmin(uh2 a, uh2 b){ uh2 r; asm("v_pk_min_f16 %0, %1, %2" : "=v"(r) : "v"(a), "v"(b)); return r; }
__device__ __forceinline__ uh2 pmax(uh2 a, uh2 b){ uh2 r; asm("v_pk_max_f16 %0, %1, %2" : "=v"(r) : "v"(a), "v"(b)); return r; }
__device__ __forceinline__ uh2 padd(uh2 a, uh2 b){ uh2 r; asm("v_pk_add_f16 %0, %1, %2" : "=v"(r) : "v"(a), "v"(b)); return r; }
__device__ __forceinline__ uh2 psub(uh2 a, uh2 b){ uh2 r; asm("v_pk_add_f16 %0, %1, %2 neg_lo:[0,1] neg_hi:[0,1]" : "=v"(r) : "v"(a), "v"(b)); return r; }
__device__ __forceinline__ uh2 pnfma(uh2 s, uh2 d){ uh2 r; asm("v_pk_fma_f16 %0, %1, %2, %2 neg_lo:[1,0,0] neg_hi:[1,0,0]" : "=v"(r) : "v"(s), "v"(d)); return r; }
__device__ __forceinline__ uh2 pmin3(uh2 a, uh2 b, uh2 c){ return pmin(pmin(a,b),c); }
__device__ __forceinline__ uh2 pmax3(uh2 a, uh2 b, uh2 c){ return pmax(pmax(a,b),c); }
// forced single-instruction funnel shift: result = (lo.y, hi.x)
__device__ __forceinline__ uh2 alignh(uh2 lo, uh2 hi){
    uh2 r; asm("v_alignbit_b32 %0, %1, %2, 16" : "=v"(r) : "v"(hi), "v"(lo)); return r;
}
// packed f32x2 -> f16x2 in ONE instruction (RTZ; <=1 ulp vs RN, cancels in ratio)
__device__ __forceinline__ uh2 pkrtz(float x, float y){
    uh2 r; asm("v_cvt_pkrtz_f16_f32 %0, %1, %2" : "=v"(r) : "v"(x), "v"(y)); return r;
}
__device__ __forceinline__ float lo_f(uh2 v){ union { uh2 u; __half2 h; } c; c.u = v; return __low2float(c.h); }
__device__ __forceinline__ float hi_f(uh2 v){ union { uh2 u; __half2 h; } c; c.u = v; return __high2float(c.h); }

// ---- DPP full-wave lane shifts (VALU, no DS pipe); invalid lane <- old ----
__device__ __forceinline__ uh2 dshr1(uh2 v, unsigned old){   // lane i <- lane i-1
    return (uh2)__builtin_amdgcn_update_dpp((int)old, (int)v, 0x138, 0xF, 0xF, false);
}
__device__ __forceinline__ uh2 dshl1(uh2 v, unsigned old){   // lane i <- lane i+1
    return (uh2)__builtin_amdgcn_update_dpp((int)old, (int)v, 0x130, 0xF, 0xF, false);
}

// one full 512-wide row: lane l holds halves [8l..8l+7] in 4 packed regs
struct R4 { uh2 a, b, c, d; };
__device__ __forceinline__ R4 r4splat(uh2 v){ R4 r; r.a=v; r.b=v; r.c=v; r.d=v; return r; }
// raw load (NO conversion -> wait sinks to the cvt, 2 steps later)
__device__ __forceinline__ void ldraw(const float* p, float4& u, float4& v){
    u = *(const float4*)p; v = *(const float4*)(p + 4);
}
__device__ __forceinline__ R4 cvtrow(const float4& u, const float4& v){
    R4 r; r.a = pkrtz(u.x,u.y); r.b = pkrtz(u.z,u.w); r.c = pkrtz(v.x,v.y); r.d = pkrtz(v.z,v.w);
    return r;
}
__device__ __forceinline__ R4 vmin3(const R4& x, const R4& y, const R4& z){
    R4 r; r.a=pmin3(x.a,y.a,z.a); r.b=pmin3(x.b,y.b,z.b); r.c=pmin3(x.c,y.c,z.c); r.d=pmin3(x.d,y.d,z.d); return r;
}
__device__ __forceinline__ R4 vmax3(const R4& x, const R4& y, const R4& z){
    R4 r; r.a=pmax3(x.a,y.a,z.a); r.b=pmax3(x.b,y.b,z.b); r.c=pmax3(x.c,y.c,z.c); r.d=pmax3(x.d,y.d,z.d); return r;
}
__device__ __forceinline__ R4 rmin(const R4& x, const R4& y){
    R4 r; r.a=pmin(x.a,y.a); r.b=pmin(x.b,y.b); r.c=pmin(x.c,y.c); r.d=pmin(x.d,y.d); return r;
}
__device__ __forceinline__ R4 relusub(const R4& p, const R4& d){
    R4 r; r.a=pmax(psub(p.a,d.a),0u); r.b=pmax(psub(p.b,d.b),0u);
          r.c=pmax(psub(p.c,d.c),0u); r.d=pmax(psub(p.d,d.d),0u); return r;
}
// s += d*(1-s)  (relu provably redundant for s,d in [0,1])
__device__ __forceinline__ void skupd2(R4& s, const R4& d){
    s.a = padd(s.a, pnfma(s.a,d.a));
    s.b = padd(s.b, pnfma(s.b,d.b));
    s.c = padd(s.c, pnfma(s.c,d.c));
    s.d = padd(s.d, pnfma(s.d,d.d));
}
__device__ __forceinline__ R4 hminLR(const R4& x){
    uh2 L  = dshr1(x.d, PINF2);
    uh2 Rv = dshl1(x.a, PINF2);
    uh2 s0=alignh(L,x.a), s1=alignh(x.a,x.b), s2=alignh(x.b,x.c), s3=alignh(x.c,x.d), s4=alignh(x.d,Rv);
    R4 m; m.a=pmin(s0,s1); m.b=pmin(s1,s2); m.c=pmin(s2,s3); m.d=pmin(s3,s4); return m;
}
__device__ __forceinline__ R4 hmax3w(const R4& x){
    uh2 L  = dshr1(x.d, NINF2);
    uh2 Rv = dshl1(x.a, NINF2);
    uh2 s0=alignh(L,x.a), s1=alignh(x.a,x.b), s2=alignh(x.b,x.c), s3=alignh(x.c,x.d), s4=alignh(x.d,Rv);
    R4 m; m.a=pmax3(s0,x.a,s1); m.b=pmax3(s1,x.b,s2); m.c=pmax3(s2,x.c,s3); m.d=pmax3(s3,x.d,s4); return m;
}
__device__ __forceinline__ void finred(const R4& skF, const float4& o1, const float4& o2,
                                       float& sa, float& sb){
    float c0=lo_f(skF.a), c1=hi_f(skF.a), c2=lo_f(skF.b), c3=hi_f(skF.b);
    float c4=lo_f(skF.c), c5=hi_f(skF.c), c6=lo_f(skF.d), c7=hi_f(skF.d);
    sa += ((c0+c1)+(c2+c3)) + ((c4+c5)+(c6+c7));
    sb += ((c0*o1.x + c1*o1.y) + (c2*o1.z + c3*o1.w))
        + ((c4*o2.x + c5*o2.y) + (c6*o2.z + c7*o2.w));
}

// ---------- FAST step: interior bands, no row guards ----------
// ALL loads unconditional (clamped addresses) -> static vmcnt counting.
__device__ __forceinline__ void step_fast(
    int g, int y0, int y1,
    const float* __restrict__ img, const float* __restrict__ oth,
    R4& i2, R4& i1, float4& pr1, float4& pr2,
    R4& e1p, R4& e1pp, R4& e2p, R4& e2pp, R4& e3p, R4& e3pp, R4& e4p, R4& e4pp,
    R4& skB, R4& skD1, R4& skD2, R4& skF,
    float4& oc1, float4& oc2, float4& on1, float4& on2,
    float& sa, float& sb)
{
    R4 i0 = cvtrow(pr1, pr2);                          // wait lands here (2-step-old load)
    {   // issue load of row g+2 into the freed staging pair (clamped)
        int gn = (g + 2 < HH) ? (g + 2) : (HH - 1);
        ldraw(img + (size_t)gn * WW, pr1, pr2);
    }
    const int  yf  = g - 5;
    const bool fin = (yf >= y0) && (yf < y1);
    {   // other-row for NEXT step, unconditional (clamped within band)
        int yfp = yf + 1;
        yfp = yfp < y0 ? y0 : (yfp >= y1 ? y1 - 1 : yfp);
        on1 = *(const float4*)(oth + (size_t)yfp * WW);
        on2 = *(const float4*)(oth + (size_t)yfp * WW + 4);
    }

    R4 e1n = rmin(vmin3(i2, i1, i0), hminLR(i1));
    R4 d1  = hmax3w(vmax3(e1pp, e1p, e1n));            // dilate(e1) @ g-2
    skB = relusub(i2, d1);

    R4 e2n = rmin(vmin3(e1pp, e1p, e1n), hminLR(e1p));
    R4 d2  = hmax3w(vmax3(e2pp, e2p, e2n));            // @ g-3
    skupd2(skD1, relusub(e1pp, d2));

    R4 e3n = rmin(vmin3(e2pp, e2p, e2n), hminLR(e2p));
    R4 d3  = hmax3w(vmax3(e3pp, e3p, e3n));            // @ g-4
    skupd2(skD2, relusub(e2pp, d3));

    R4 e4n = rmin(vmin3(e3pp, e3p, e3n), hminLR(e3p));
    R4 d4  = hmax3w(vmax3(e4pp, e4p, e4n));            // @ g-5
    skupd2(skF, relusub(e3pp, d4));

    if (fin) finred(skF, oc1, oc2, sa, sb);

    i2 = i1; i1 = i0;
    e1pp = e1n; e2pp = e2n; e3pp = e3n; e4pp = e4n;    // caller swaps (p,pp)
}

// ---------- GUARD step: bands 0 / NBANDS-1 ----------
__device__ __forceinline__ void step_guard(
    int g, int y0, int y1,
    const float* __restrict__ img, const float* __restrict__ oth,
    R4& i2, R4& i1, float4& pr1, float4& pr2,
    R4& e1p, R4& e1pp, R4& e2p, R4& e2pp, R4& e3p, R4& e3pp,
    R4& h1p, R4& h1pp, R4& h2p, R4& h2pp, R4& h3p, R4& h3pp,
    R4& h4p, R4& h4pp,
    R4& skB, R4& skD1, R4& skD2, R4& skF,
    float4& oc1, float4& oc2, float4& on1, float4& on2,
    float& sa, float& sb)
{
    // consume-time select reproduces load-time +inf splat exactly
    R4 i0 = ((unsigned)g < (unsigned)HH) ? cvtrow(pr1, pr2) : r4splat(PINF2);
    {   // clamped-address load (value discarded at consume when OOB)
        int gn = g + 2;
        gn = gn < 0 ? 0 : (gn >= HH ? HH - 1 : gn);
        ldraw(img + (size_t)gn * WW, pr1, pr2);
    }
    const int  yf  = g - 5;
    const bool fin = (yf >= y0) && (yf < y1);
    {   // unconditional clamped oth load
        int yfp = yf + 1;
        yfp = yfp < y0 ? y0 : (yfp >= y1 ? y1 - 1 : yfp);
        on1 = *(const float4*)(oth + (size_t)yfp * WW);
        on2 = *(const float4*)(oth + (size_t)yfp * WW + 4);
    }

    R4 e1n = rmin(vmin3(i2, i1, i0), hminLR(i1));
    R4 h1n = hmax3w(e1n);
    if ((unsigned)(g - 1) >= (unsigned)HH) { e1n = r4splat(PINF2); h1n = r4splat(NINF2); }
    R4 d1 = vmax3(h1pp, h1p, h1n);
    skB = relusub(i2, d1);

    R4 e2n = rmin(vmin3(e1pp, e1p, e1n), hminLR(e1p));
    R4 h2n = hmax3w(e2n);
    if ((unsigned)(g - 2) >= (unsigned)HH) { e2n = r4splat(PINF2); h2n = r4splat(NINF2); }
    R4 d2 = vmax3(h2pp, h2p, h2n);
    skupd2(skD1, relusub(e1pp, d2));

    R4 e3n = rmin(vmin3(e2pp, e2p, e2n), hminLR(e2p));
    R4 h3n = hmax3w(e3n);
    if ((unsigned)(g - 3) >= (unsigned)HH) { e3n = r4splat(PINF2); h3n = r4splat(NINF2); }
    R4 d3 = vmax3(h3pp, h3p, h3n);
    skupd2(skD2, relusub(e2pp, d3));

    R4 e4n = rmin(vmin3(e3pp, e3p, e3n), hminLR(e3p));
    R4 h4n = hmax3w(e4n);
    if ((unsigned)(g - 4) >= (unsigned)HH) { h4n = r4splat(NINF2); }
    R4 d4 = vmax3(h4pp, h4p, h4n);
    skupd2(skF, relusub(e3pp, d4));

    if (fin) finred(skF, oc1, oc2, sa, sb);

    i2 = i1; i1 = i0;
    e1pp = e1n; e2pp = e2n; e3pp = e3n;
    h1pp = h1n; h2pp = h2n; h3pp = h3n; h4pp = h4n;
}

__global__ __launch_bounds__(256, 2)
void cldice_stream_k(const float* __restrict__ y_pred,
                     const float* __restrict__ y_true,
                     float2* __restrict__ partials, int B)
{
    const int lane = threadIdx.x & 63;
    const int wid  = threadIdx.x >> 6;
    const int wave = blockIdx.x * 4 + wid;
    const int nPerChain = B * NBANDS;
    if (wave >= 2 * nPerChain) return;
    const int chain = wave / nPerChain;
    const int rem   = wave - chain * nPerChain;
    const int im    = rem >> 5;                 // NBANDS == 32
    const int band  = rem & (NBANDS - 1);
    const int y0 = band * BAND;
    const int y1 = y0 + BAND;

    const float* __restrict__ img = (chain ? y_true : y_pred) + (size_t)im * NPIX + lane * 8;
    const float* __restrict__ oth = (chain ? y_pred : y_true) + (size_t)im * NPIX + lane * 8;

    R4 sk0 = r4splat(0u), sk1 = sk0, sk2 = sk0, sk3 = sk0;
    float sa = 0.f, sb = 0.f;
    const int g0 = y0 - 5;
    float4 oA1 = make_float4(0,0,0,0), oA2 = oA1, oB1 = oA1, oB2 = oA1;

    // raw staging pairs: pA = row consumed at even steps, pB = odd steps
    float4 pA1, pA2, pB1, pB2;
    {
        int r0 = g0 < 0 ? 0 : g0;
        int r1 = g0 + 1 < 0 ? 0 : g0 + 1;
        ldraw(img + (size_t)r0 * WW, pA1, pA2);
        ldraw(img + (size_t)r1 * WW, pB1, pB2);
    }

    if (band == 0 || band == NBANDS - 1) {
        // -------- guarded path (image top/bottom) --------
        R4 i2 = r4splat(PINF2), i1 = i2;
        R4 e1A = i2, e1B = i2, e2A = i2, e2B = i2, e3A = i2, e3B = i2;
        R4 h1A = r4splat(NINF2), h1B = h1A, h2A = h1A, h2B = h1A;
        R4 h3A = h1A, h3B = h1A, h4A = h1A, h4B = h1A;

#define STEPG(U, E1P,E1PP, E2P,E2PP, E3P,E3PP, H1P,H1PP, H2P,H2PP, H3P,H3PP, H4P,H4PP, SKB,SKD1,SKD2,SKF, PR1,PR2, OC1,OC2,ON1,ON2) \
        step_guard(g0 + sbase + U, y0, y1, img, oth, i2, i1, PR1, PR2, \
                   E1P,E1PP, E2P,E2PP, E3P,E3PP, H1P,H1PP, H2P,H2PP, H3P,H3PP, H4P,H4PP, \
                   SKB,SKD1,SKD2,SKF, OC1,OC2,ON1,ON2, sa, sb)
        for (int sbase = 0; sbase < 24; sbase += 4) {
            STEPG(0, e1A,e1B, e2A,e2B, e3A,e3B, h1A,h1B, h2A,h2B, h3A,h3B, h4A,h4B, sk1,sk0,sk3,sk2, pA1,pA2, oA1,oA2,oB1,oB2);
            STEPG(1, e1B,e1A, e2B,e2A, e3B,e3A, h1B,h1A, h2B,h2A, h3B,h3A, h4B,h4A, sk2,sk1,sk0,sk3, pB1,pB2, oB1,oB2,oA1,oA2);
            STEPG(2, e1A,e1B, e2A,e2B, e3A,e3B, h1A,h1B, h2A,h2B, h3A,h3B, h4A,h4B, sk3,sk2,sk1,sk0, pA1,pA2, oA1,oA2,oB1,oB2);
            STEPG(3, e1B,e1A, e2B,e2A, e3B,e3A, h1B,h1A, h2B,h2A, h3B,h3A, h4B,h4A, sk0,sk3,sk2,sk1, pB1,pB2, oB1,oB2,oA1,oA2);
        }
        {   // tail: steps 24, 25 (last fin at 25)
            const int sbase = 24;
            STEPG(0, e1A,e1B, e2A,e2B, e3A,e3B, h1A,h1B, h2A,h2B, h3A,h3B, h4A,h4B, sk1,sk0,sk3,sk2, pA1,pA2, oA1,oA2,oB1,oB2);
            STEPG(1, e1B,e1A, e2B,e2A, e3B,e3A, h1B,h1A, h2B,h2A, h3B,h3A, h4B,h4A, sk2,sk1,sk0,sk3, pB1,pB2, oB1,oB2,oA1,oA2);
        }
#undef STEPG
    } else {
        // -------- fast path (interior bands; all rows real; init outside frontier) --------
        R4 i2 = r4splat(PINF2), i1 = i2;
        R4 e1A = i2, e1B = i2, e2A = i2, e2B = i2;
        R4 e3A = i2, e3B = i2, e4A = i2, e4B = i2;

#define STEPF(U, E1P,E1PP, E2P,E2PP, E3P,E3PP, E4P,E4PP, SKB,SKD1,SKD2,SKF, PR1,PR2, OC1,OC2,ON1,ON2) \
        step_fast(g0 + sbase + U, y0, y1, img, oth, i2, i1, PR1, PR2, \
                  E1P,E1PP, E2P,E2PP, E3P,E3PP, E4P,E4PP, SKB,SKD1,SKD2,SKF, \
                  OC1,OC2,ON1,ON2, sa, sb)
        for (int sbase = 0; sbase < 24; sbase += 4) {
            STEPF(0, e1A,e1B, e2A,e2B, e3A,e3B, e4A,e4B, sk1,sk0,sk3,sk2, pA1,pA2, oA1,oA2,oB1,oB2);
            STEPF(1, e1B,e1A, e2B,e2A, e3B,e3A, e4B,e4A, sk2,sk1,sk0,sk3, pB1,pB2, oB1,oB2,oA1,oA2);
            STEPF(2, e1A,e1B, e2A,e2B, e3A,e3B, e4A,e4B, sk3,sk2,sk1,sk0, pA1,pA2, oA1,oA2,oB1,oB2);
            STEPF(3, e1B,e1A, e2B,e2A, e3B,e3A, e4B,e4A, sk0,sk3,sk2,sk1, pB1,pB2, oB1,oB2,oA1,oA2);
        }
        {   // tail: steps 24, 25
            const int sbase = 24;
            STEPF(0, e1A,e1B, e2A,e2B, e3A,e3B, e4A,e4B, sk1,sk0,sk3,sk2, pA1,pA2, oA1,oA2,oB1,oB2);
            STEPF(1, e1B,e1A, e2B,e2A, e3B,e3A, e4B,e4A, sk2,sk1,sk0,sk3, pB1,pB2, oB1,oB2,oA1,oA2);
        }
#undef STEPF
    }

#pragma unroll
    for (int off = 32; off; off >>= 1) {
        sa += __shfl_down(sa, off);
        sb += __shfl_down(sb, off);
    }
    if (lane == 0) partials[wave] = make_float2(sb, sa);   // (.x = sum skel*other, .y = sum skel)
}

__global__ void cldice_final_k(const float2* __restrict__ partials, int nW,
                               float* __restrict__ out)
{
    double s0 = 0, s1 = 0, s2 = 0, s3 = 0;
    for (int i = threadIdx.x; i < nW; i += 256) {
        float2 p = partials[i];        s0 += p.x; s1 += p.y;   // chain 0: skel_pred
        float2 q = partials[nW + i];   s2 += q.x; s3 += q.y;   // chain 1: skel_true
    }
#pragma unroll
    for (int off = 32; off; off >>= 1) {
        s0 += __shfl_down(s0, off);
        s1 += __shfl_down(s1, off);
        s2 += __shfl_down(s2, off);
        s3 += __shfl_down(s3, off);
    }
    __shared__ double sm[4][4];
    int wid = threadIdx.x >> 6, lane = threadIdx.x & 63;
    if (lane == 0) { sm[0][wid] = s0; sm[1][wid] = s1; sm[2][wid] = s2; sm[3][wid] = s3; }
    __syncthreads();
    if (threadIdx.x == 0) {
        double S0 = sm[0][0] + sm[0][1] + sm[0][2] + sm[0][3];
        double S1 = sm[1][0] + sm[1][1] + sm[1][2] + sm[1][3];
        double S2 = sm[2][0] + sm[2][1] + sm[2][2] + sm[2][3];
        double S3 = sm[3][0] + sm[3][1] + sm[3][2] + sm[3][3];
        double tprec = (S0 + 1.0) / (S1 + 1.0);
        double tsens = (S2 + 1.0) / (S3 + 1.0);
        out[0] = (float)(1.0 - 2.0 * (tprec * tsens) / (tprec + tsens));
    }
}

extern "C" void kernel_launch(void* const* d_in, const int* in_sizes, int n_in,
                              void* d_out, int out_size, void* d_ws, size_t ws_size,
                              hipStream_t stream)
{
    const float* y_pred = (const float*)d_in[0];
    const float* y_true = (const float*)d_in[1];
    const int B = in_sizes[0] / NPIX;          // 32 images

    float2* partials = (float2*)d_ws;          // 2*B*NBANDS float2 = 16 KB
    const int nWaves = 2 * B * NBANDS;
    const int blocks = (nWaves + 3) / 4;       // 4 waves per 256-thread block
    cldice_stream_k<<<blocks, 256, 0, stream>>>(y_pred, y_true, partials, B);

    cldice_final_k<<<1, 256, 0, stream>>>(partials, B * NBANDS, (float*)d_out);
}